// Round 2
// baseline (2575.415 us; speedup 1.0000x reference)
//
#include <hip/hip_runtime.h>
#include <stdint.h>

#define NB 256

// ---------------- kernels ----------------

// count in-degree over col (= ei[E + e]) via atomics
__global__ void k_deg(const int* __restrict__ ei, int E, float* __restrict__ deg) {
    int e = blockIdx.x * blockDim.x + threadIdx.x;
    if (e < E) {
        int c = ei[E + e];
        atomicAdd(&deg[c], 1.0f);
    }
}

// dinv = rsqrt(deg + 1)  (+1 = self-loop)
__global__ void k_dinv(const float* __restrict__ deg, float* __restrict__ dinv, int n) {
    int v = blockIdx.x * blockDim.x + threadIdx.x;
    if (v < n) dinv[v] = rsqrtf(deg[v] + 1.0f);
}

// layer-1 transform: hs[v][f] = ([x0,x1,y1] @ W1)[f] * dinv[v]   (W1 is [3][32])
__global__ void k_t1(const float* __restrict__ x, const float* __restrict__ y1,
                     const float* __restrict__ W1, const float* __restrict__ dinv,
                     float* __restrict__ hs, int n) {
    int t = blockIdx.x * blockDim.x + threadIdx.x;
    if (t >= n * 32) return;
    int v = t >> 5, f = t & 31;
    float a = x[2 * v], b = x[2 * v + 1], c = y1[v];
    float s = a * W1[f] + b * W1[32 + f] + c * W1[64 + f];
    hs[t] = s * dinv[v];
}

// generic 32-wide transform: hs[v][f] = (hin[v] @ W)[f] * dinv[v]   (W is [32][32])
__global__ void k_t2(const float* __restrict__ hin, const float* __restrict__ W,
                     const float* __restrict__ dinv, float* __restrict__ hs, int n) {
    int t = blockIdx.x * blockDim.x + threadIdx.x;
    if (t >= n * 32) return;
    int v = t >> 5, f = t & 31;
    const float* hrow = hin + (size_t)v * 32;
    float s = 0.0f;
#pragma unroll
    for (int k = 0; k < 32; ++k) s += hrow[k] * W[k * 32 + f];
    hs[t] = s * dinv[v];
}

// 32-channel edge scatter-add: agg[col][f] += hs[row][f]
__global__ void k_edge32(const int* __restrict__ ei, int E,
                         const float* __restrict__ hs, float* __restrict__ agg) {
    long long t = (long long)blockIdx.x * blockDim.x + threadIdx.x;
    if (t >= (long long)E * 32) return;
    int e = (int)(t >> 5);
    int f = (int)(t & 31);
    int r = ei[e];
    int c = ei[E + e];
    atomicAdd(&agg[(size_t)c * 32 + f], hs[(size_t)r * 32 + f]);
}

// finalize: hout[v][f] = relu?( dinv[v]*(agg[v][f] + hs[v][f]) + b[f] )
__global__ void k_fin(const float* __restrict__ agg, const float* __restrict__ hs,
                      const float* __restrict__ dinv, const float* __restrict__ b,
                      float* __restrict__ hout, int n, int do_relu) {
    int t = blockIdx.x * blockDim.x + threadIdx.x;
    if (t >= n * 32) return;
    int v = t >> 5, f = t & 31;
    float val = dinv[v] * (agg[t] + hs[t]) + b[f];
    if (do_relu) val = fmaxf(val, 0.0f);
    hout[t] = val;
}

// layer-3 transform: hs3[v] = (h2[v] @ W3) * dinv[v]   (W3 is [32][1])
__global__ void k_t3(const float* __restrict__ hin, const float* __restrict__ W3,
                     const float* __restrict__ dinv, float* __restrict__ hs3, int n) {
    int v = blockIdx.x * blockDim.x + threadIdx.x;
    if (v >= n) return;
    const float* hrow = hin + (size_t)v * 32;
    float s = 0.0f;
#pragma unroll
    for (int k = 0; k < 32; ++k) s += hrow[k] * W3[k];
    hs3[v] = s * dinv[v];
}

// scalar edge scatter-add: agg[col] += hs3[row]
__global__ void k_edge1(const int* __restrict__ ei, int E,
                        const float* __restrict__ hs3, float* __restrict__ agg) {
    int e = blockIdx.x * blockDim.x + threadIdx.x;
    if (e >= E) return;
    int r = ei[e];
    int c = ei[E + e];
    atomicAdd(&agg[c], hs3[r]);
}

// scalar finalize (in-place on agg): out[v] = dinv[v]*(agg[v]+hs3[v]) + b
__global__ void k_fin1(float* __restrict__ out, const float* __restrict__ hs3,
                       const float* __restrict__ dinv, const float* __restrict__ b3,
                       int n) {
    int v = blockIdx.x * blockDim.x + threadIdx.x;
    if (v >= n) return;
    out[v] = dinv[v] * (out[v] + hs3[v]) + b3[0];
}

// ---------------- launch ----------------

extern "C" void kernel_launch(void* const* d_in, const int* in_sizes, int n_in,
                              void* d_out, int out_size, void* d_ws, size_t ws_size,
                              hipStream_t stream) {
    const float* x  = (const float*)d_in[0];
    const float* y1 = (const float*)d_in[1];
    const int*   ei = (const int*)d_in[2];   // int32! harness converts integer inputs
    const float* W1 = (const float*)d_in[3];
    const float* b1 = (const float*)d_in[4];
    const float* W2 = (const float*)d_in[5];
    const float* b2 = (const float*)d_in[6];
    const float* W3 = (const float*)d_in[7];
    const float* b3 = (const float*)d_in[8];
    float* out = (float*)d_out;

    const int n = in_sizes[1];          // 250000 nodes
    const int E = in_sizes[2] / 2;      // 8000000 edges

    // workspace layout (bytes, 256-aligned)
    char* ws = (char*)d_ws;
    size_t off = 0;
    auto alloc = [&](size_t bytes) { char* p = ws + off; off += (bytes + 255) & ~(size_t)255; return p; };
    float* bufA = (float*)alloc((size_t)n * 32 * sizeof(float)); // hs / agg ping-pong
    float* bufB = (float*)alloc((size_t)n * 32 * sizeof(float));
    float* deg  = (float*)alloc((size_t)n * sizeof(float));
    float* dinv = (float*)alloc((size_t)n * sizeof(float));
    float* hs3  = (float*)alloc((size_t)n * sizeof(float));
    (void)ws_size;

    const int gN   = (n + NB - 1) / NB;
    const int gN32 = (n * 32 + NB - 1) / NB;
    const int gE   = (E + NB - 1) / NB;
    const long long tE32 = (long long)E * 32;
    const int gE32 = (int)((tE32 + NB - 1) / NB);

    // degree + dinv
    hipMemsetAsync(deg, 0, (size_t)n * sizeof(float), stream);
    k_deg<<<gE, NB, 0, stream>>>(ei, E, deg);
    k_dinv<<<gN, NB, 0, stream>>>(deg, dinv, n);

    // ---- layer 1: hs in bufA, agg in bufB, h1 -> bufA (in-place fin) ----
    k_t1<<<gN32, NB, 0, stream>>>(x, y1, W1, dinv, bufA, n);
    hipMemsetAsync(bufB, 0, (size_t)n * 32 * sizeof(float), stream);
    k_edge32<<<gE32, NB, 0, stream>>>(ei, E, bufA, bufB);
    k_fin<<<gN32, NB, 0, stream>>>(bufB, bufA, dinv, b1, bufA, n, 1);

    // ---- layer 2: h1 in bufA -> hs in bufB, agg in bufA (h1 dead after t2) ----
    k_t2<<<gN32, NB, 0, stream>>>(bufA, W2, dinv, bufB, n);
    hipMemsetAsync(bufA, 0, (size_t)n * 32 * sizeof(float), stream);
    k_edge32<<<gE32, NB, 0, stream>>>(ei, E, bufB, bufA);
    k_fin<<<gN32, NB, 0, stream>>>(bufA, bufB, dinv, b2, bufB, n, 1);

    // ---- layer 3: h2 in bufB -> hs3 (scalar), agg in d_out ----
    k_t3<<<gN, NB, 0, stream>>>(bufB, W3, dinv, hs3, n);
    hipMemsetAsync(out, 0, (size_t)n * sizeof(float), stream);
    k_edge1<<<gE, NB, 0, stream>>>(ei, E, hs3, out);
    k_fin1<<<gN, NB, 0, stream>>>(out, hs3, dinv, b3, n);
}

// Round 5
// 1639.018 us; speedup vs baseline: 1.5713x; 1.5713x over previous
//
#include <hip/hip_runtime.h>
#include <stdint.h>

#define NB 256

// ---------------- degree / norm ----------------

__global__ void k_deg(const int* __restrict__ ei, int E, int* __restrict__ deg) {
    int e = blockIdx.x * blockDim.x + threadIdx.x;
    if (e < E) atomicAdd(&deg[ei[E + e]], 1);
}

__global__ void k_dinv(const int* __restrict__ deg, float* __restrict__ dinv, int n) {
    int v = blockIdx.x * blockDim.x + threadIdx.x;
    if (v < n) dinv[v] = rsqrtf((float)deg[v] + 1.0f);
}

// ---------------- CSR build: scan + scatter ----------------

// per-block exclusive scan of deg -> tmp, block totals -> bsum
__global__ void k_scan_block(const int* __restrict__ deg, int n,
                             int* __restrict__ tmp, int* __restrict__ bsum) {
    __shared__ int sm[NB];
    int tid = threadIdx.x;
    int i = blockIdx.x * NB + tid;
    int v = (i < n) ? deg[i] : 0;
    sm[tid] = v;
    __syncthreads();
    for (int off = 1; off < NB; off <<= 1) {
        int t = (tid >= off) ? sm[tid - off] : 0;
        __syncthreads();
        sm[tid] += t;
        __syncthreads();
    }
    if (i < n) tmp[i] = sm[tid] - v;           // exclusive within block
    if (tid == NB - 1) bsum[blockIdx.x] = sm[tid];
}

// single-block scan of block sums -> exclusive offsets (nb <= 1024)
__global__ void k_scan_bsum(const int* __restrict__ bsum, int nb, int* __restrict__ bexcl) {
    __shared__ int sm[1024];
    int tid = threadIdx.x;
    int v = (tid < nb) ? bsum[tid] : 0;
    sm[tid] = v;
    __syncthreads();
    for (int off = 1; off < 1024; off <<= 1) {
        int t = (tid >= off) ? sm[tid - off] : 0;
        __syncthreads();
        sm[tid] += t;
        __syncthreads();
    }
    if (tid < nb) bexcl[tid] = sm[tid] - v;
}

// rowptr[i] = tmp[i] + bexcl[i/NB]; rowptr[n] = E; cursor[i] = rowptr[i]
__global__ void k_scan_add(const int* __restrict__ tmp, const int* __restrict__ bexcl,
                           int n, int E, int* __restrict__ rowptr, int* __restrict__ cursor) {
    int i = blockIdx.x * blockDim.x + threadIdx.x;
    if (i > n) return;
    if (i == n) { rowptr[n] = E; return; }
    int r = tmp[i] + bexcl[i >> 8];            // NB == 256
    rowptr[i] = r;
    cursor[i] = r;
}

// csr_row[pos] = row, pos = fetch-add on cursor[col]
// NOTE: segment-internal order is non-deterministic; consumers must be
// order-insensitive (double accumulation in k_agg*).
__global__ void k_scatter(const int* __restrict__ ei, int E,
                          int* __restrict__ cursor, int* __restrict__ csr_row) {
    int e = blockIdx.x * blockDim.x + threadIdx.x;
    if (e >= E) return;
    int r = ei[e];
    int c = ei[E + e];
    int pos = atomicAdd(&cursor[c], 1);
    csr_row[pos] = r;
}

// ---------------- transforms ----------------

// hs[v][f] = ([x0,x1,y1] @ W1)[f] * dinv[v]
__global__ void k_t1(const float* __restrict__ x, const float* __restrict__ y1,
                     const float* __restrict__ W1, const float* __restrict__ dinv,
                     float* __restrict__ hs, int n) {
    int t = blockIdx.x * blockDim.x + threadIdx.x;
    if (t >= n * 32) return;
    int v = t >> 5, f = t & 31;
    float a = x[2 * v], b = x[2 * v + 1], c = y1[v];
    float s = a * W1[f] + b * W1[32 + f] + c * W1[64 + f];
    hs[t] = s * dinv[v];
}

// hs[v][f] = (hin[v] @ W)[f] * dinv[v]   (W is [32][32])
__global__ void k_t2(const float* __restrict__ hin, const float* __restrict__ W,
                     const float* __restrict__ dinv, float* __restrict__ hs, int n) {
    int t = blockIdx.x * blockDim.x + threadIdx.x;
    if (t >= n * 32) return;
    int v = t >> 5, f = t & 31;
    const float* hrow = hin + (size_t)v * 32;
    float s = 0.0f;
#pragma unroll
    for (int k = 0; k < 32; ++k) s += hrow[k] * W[k * 32 + f];
    hs[t] = s * dinv[v];
}

// hs3[v] = (h2[v] @ W3) * dinv[v]
__global__ void k_t3(const float* __restrict__ hin, const float* __restrict__ W3,
                     const float* __restrict__ dinv, float* __restrict__ hs3, int n) {
    int v = blockIdx.x * blockDim.x + threadIdx.x;
    if (v >= n) return;
    const float* hrow = hin + (size_t)v * 32;
    float s = 0.0f;
#pragma unroll
    for (int k = 0; k < 32; ++k) s += hrow[k] * W3[k];
    hs3[v] = s * dinv[v];
}

// ---------------- atomic-free pull aggregation (fused finalize) ----------------
// double accumulator: per-node sum exact regardless of csr segment order ->
// replay-deterministic to <=1 ulp of f32.

// one 32-lane group per node, lane = channel
__global__ void k_agg32(const int* __restrict__ rowptr, const int* __restrict__ csr_row,
                        const float* __restrict__ hs, const float* __restrict__ dinv,
                        const float* __restrict__ b, float* __restrict__ out,
                        int n, int do_relu) {
    int t = blockIdx.x * blockDim.x + threadIdx.x;
    int g = t >> 5;                 // node
    int f = t & 31;                 // channel
    if (g >= n) return;
    int s = rowptr[g], e = rowptr[g + 1];
    double acc = 0.0;
    for (int j = s; j < e; j += 32) {
        int cnt = min(32, e - j);
        int rj = (j + f < e) ? csr_row[j + f] : 0;   // coalesced batch of edge sources
        for (int k = 0; k < cnt; ++k) {
            int r = __shfl(rj, k, 32);
            acc += (double)hs[(size_t)r * 32 + f];   // coalesced 128B gather
        }
    }
    float val = dinv[g] * ((float)acc + hs[(size_t)g * 32 + f]) + b[f];
    if (do_relu) val = fmaxf(val, 0.0f);
    out[(size_t)g * 32 + f] = val;
}

// one 32-lane group per node, lanes stride edges, shuffle-reduce
__global__ void k_agg1(const int* __restrict__ rowptr, const int* __restrict__ csr_row,
                       const float* __restrict__ hs3, const float* __restrict__ dinv,
                       const float* __restrict__ b3, float* __restrict__ out, int n) {
    int t = blockIdx.x * blockDim.x + threadIdx.x;
    int g = t >> 5;
    int l = t & 31;
    if (g >= n) return;
    int s = rowptr[g], e = rowptr[g + 1];
    double acc = 0.0;
    for (int j = s + l; j < e; j += 32) acc += (double)hs3[csr_row[j]];
    for (int off = 16; off > 0; off >>= 1) acc += __shfl_down(acc, off, 32);
    if (l == 0) out[g] = dinv[g] * ((float)acc + hs3[g]) + b3[0];
}

// ---------------- launch ----------------

extern "C" void kernel_launch(void* const* d_in, const int* in_sizes, int n_in,
                              void* d_out, int out_size, void* d_ws, size_t ws_size,
                              hipStream_t stream) {
    const float* x  = (const float*)d_in[0];
    const float* y1 = (const float*)d_in[1];
    const int*   ei = (const int*)d_in[2];
    const float* W1 = (const float*)d_in[3];
    const float* b1 = (const float*)d_in[4];
    const float* W2 = (const float*)d_in[5];
    const float* b2 = (const float*)d_in[6];
    const float* W3 = (const float*)d_in[7];
    const float* b3 = (const float*)d_in[8];
    float* out = (float*)d_out;

    const int n = in_sizes[1];          // 250000
    const int E = in_sizes[2] / 2;      // 8000000

    char* ws = (char*)d_ws;
    size_t off = 0;
    auto alloc = [&](size_t bytes) { char* p = ws + off; off += (bytes + 255) & ~(size_t)255; return p; };
    float* bufA   = (float*)alloc((size_t)n * 32 * sizeof(float));
    float* bufB   = (float*)alloc((size_t)n * 32 * sizeof(float));
    int*   csr_row= (int*)alloc((size_t)E * sizeof(int));
    int*   deg    = (int*)alloc((size_t)n * sizeof(int));
    float* dinv   = (float*)alloc((size_t)n * sizeof(float));
    float* hs3    = (float*)alloc((size_t)n * sizeof(float));
    int*   rowptr = (int*)alloc((size_t)(n + 1) * sizeof(int));
    int*   cursor = (int*)alloc((size_t)n * sizeof(int));
    int*   tmp    = (int*)alloc((size_t)n * sizeof(int));
    int*   bsum   = (int*)alloc(1024 * sizeof(int));
    int*   bexcl  = (int*)alloc(1024 * sizeof(int));
    (void)ws_size;

    const int gN   = (n + NB - 1) / NB;
    const int gN32 = (n * 32 + NB - 1) / NB;
    const int gE   = (E + NB - 1) / NB;
    const int nb   = (n + NB - 1) / NB;        // #scan blocks (977)

    // degree + dinv
    hipMemsetAsync(deg, 0, (size_t)n * sizeof(int), stream);
    k_deg<<<gE, NB, 0, stream>>>(ei, E, deg);
    k_dinv<<<gN, NB, 0, stream>>>(deg, dinv, n);

    // CSR build
    k_scan_block<<<nb, NB, 0, stream>>>(deg, n, tmp, bsum);
    k_scan_bsum<<<1, 1024, 0, stream>>>(bsum, nb, bexcl);
    k_scan_add<<<(n + 1 + NB - 1) / NB, NB, 0, stream>>>(tmp, bexcl, n, E, rowptr, cursor);
    k_scatter<<<gE, NB, 0, stream>>>(ei, E, cursor, csr_row);

    // ---- layer 1 ----
    k_t1<<<gN32, NB, 0, stream>>>(x, y1, W1, dinv, bufA, n);
    k_agg32<<<gN32, NB, 0, stream>>>(rowptr, csr_row, bufA, dinv, b1, bufB, n, 1);

    // ---- layer 2 ----
    k_t2<<<gN32, NB, 0, stream>>>(bufB, W2, dinv, bufA, n);
    k_agg32<<<gN32, NB, 0, stream>>>(rowptr, csr_row, bufA, dinv, b2, bufB, n, 1);

    // ---- layer 3 ----
    k_t3<<<gN, NB, 0, stream>>>(bufB, W3, dinv, hs3, n);
    k_agg1<<<gN32, NB, 0, stream>>>(rowptr, csr_row, hs3, dinv, b3, out, n);
}

// Round 6
// 909.597 us; speedup vs baseline: 2.8314x; 1.8019x over previous
//
#include <hip/hip_runtime.h>
#include <stdint.h>

#define MAXBUK 1024   // buckets = ceil(n/256); 977 for n=250000

// ---------------- bucket histogram (col >> 8) ----------------
__global__ void k_hist(const int* __restrict__ ei, int E, int nbuk, int* __restrict__ bcnt) {
    __shared__ int h[MAXBUK];
    for (int b = threadIdx.x; b < nbuk; b += blockDim.x) h[b] = 0;
    __syncthreads();
    int stride = gridDim.x * blockDim.x;
    for (int e = blockIdx.x * blockDim.x + threadIdx.x; e < E; e += stride)
        atomicAdd(&h[ei[E + e] >> 8], 1);
    __syncthreads();
    for (int b = threadIdx.x; b < nbuk; b += blockDim.x)
        if (h[b]) atomicAdd(&bcnt[b], h[b]);
}

// ---------------- exclusive scan of bucket counts (nbuk <= 1024) ----------------
__global__ void k_scan(const int* __restrict__ bcnt, int nbuk, int E,
                       int* __restrict__ bbase, int* __restrict__ cursor) {
    __shared__ int sm[1024];
    int tid = threadIdx.x;
    int v = (tid < nbuk) ? bcnt[tid] : 0;
    sm[tid] = v;
    __syncthreads();
    for (int off = 1; off < 1024; off <<= 1) {
        int t = (tid >= off) ? sm[tid - off] : 0;
        __syncthreads();
        sm[tid] += t;
        __syncthreads();
    }
    if (tid < nbuk) { bbase[tid] = sm[tid] - v; cursor[tid] = sm[tid] - v; }
    if (tid == 0) bbase[nbuk] = E;
}

// ---------------- block-reservation binning ----------------
// pairs[pos] = (row << 8) | (col & 255), grouped by bucket (order within bucket
// is non-deterministic; all consumers are order-insensitive via f64 accumulation).
__global__ void k_bin(const int* __restrict__ ei, int E, int nbuk, int chunk,
                      int* __restrict__ cursor, unsigned int* __restrict__ pairs) {
    __shared__ int h[MAXBUK];
    __shared__ int base[MAXBUK];
    int start = (int)blockIdx.x * chunk;
    int end = min(start + chunk, E);
    for (int b = threadIdx.x; b < nbuk; b += blockDim.x) h[b] = 0;
    __syncthreads();
    for (int i = start + threadIdx.x; i < end; i += blockDim.x)
        atomicAdd(&h[ei[E + i] >> 8], 1);
    __syncthreads();
    for (int b = threadIdx.x; b < nbuk; b += blockDim.x) {
        int c = h[b];
        base[b] = c ? atomicAdd(&cursor[b], c) : 0;
        h[b] = 0;                      // reuse as local cursor
    }
    __syncthreads();
    for (int i = start + threadIdx.x; i < end; i += blockDim.x) {
        int r = ei[i];
        int c = ei[E + i];
        int b = c >> 8;
        int loc = atomicAdd(&h[b], 1);
        pairs[base[b] + loc] = ((unsigned)r << 8) | (unsigned)(c & 255);
    }
}

// ---------------- per-bucket degree count -> dinv ----------------
__global__ void k_dcnt(const unsigned int* __restrict__ pairs, const int* __restrict__ bbase,
                       int n, float* __restrict__ dinv) {
    __shared__ int cnt[256];
    int b = blockIdx.x;
    cnt[threadIdx.x] = 0;
    __syncthreads();
    int s = bbase[b], e = bbase[b + 1];
    for (int j = s + threadIdx.x; j < e; j += blockDim.x)
        atomicAdd(&cnt[pairs[j] & 255u], 1);
    __syncthreads();
    int col = (b << 8) + threadIdx.x;
    if (col < n) dinv[col] = rsqrtf((float)cnt[threadIdx.x] + 1.0f);
}

// ---------------- s4 table: (dinv*x0, dinv*x1, dinv*y1, dinv) ----------------
__global__ void k_s4(const float* __restrict__ x, const float* __restrict__ y1,
                     const float* __restrict__ dinv, float4* __restrict__ s4, int n) {
    int v = blockIdx.x * blockDim.x + threadIdx.x;
    if (v >= n) return;
    float d = dinv[v];
    s4[v] = make_float4(d * x[2 * v], d * x[2 * v + 1], d * y1[v], d);
}

// ---------------- fused layer 1: agg3 -> W1+ReLU -> W2*dinv -> hs2 ----------------
__global__ void k_L1(const unsigned int* __restrict__ pairs, const int* __restrict__ bbase,
                     const float4* __restrict__ s4, const float* __restrict__ W1,
                     const float* __restrict__ b1, const float* __restrict__ W2,
                     float* __restrict__ hs2, int n) {
    __shared__ double acc[256 * 3];
    int b = blockIdx.x;
    for (int i = threadIdx.x; i < 256 * 3; i += blockDim.x) acc[i] = 0.0;
    __syncthreads();
    int s = bbase[b], e = bbase[b + 1];
    for (int j = s + threadIdx.x; j < e; j += blockDim.x) {
        unsigned pk = pairs[j];
        int r = (int)(pk >> 8);
        int cl = (int)(pk & 255u);
        float4 sv = s4[r];                      // 16B gather, 4MB L2-resident table
        atomicAdd(&acc[cl * 3 + 0], (double)sv.x);
        atomicAdd(&acc[cl * 3 + 1], (double)sv.y);
        atomicAdd(&acc[cl * 3 + 2], (double)sv.z);
    }
    __syncthreads();
    int f = threadIdx.x & 31;
    int g = threadIdx.x >> 5;                   // 8 groups of 32
    for (int ci = g; ci < 256; ci += 8) {
        int col = (b << 8) + ci;
        if (col >= n) continue;                 // group-uniform
        float4 sc = s4[col];
        float a0 = (float)acc[ci * 3 + 0] + sc.x;   // + self loop
        float a1 = (float)acc[ci * 3 + 1] + sc.y;
        float a2 = (float)acc[ci * 3 + 2] + sc.z;
        float d = sc.w;
        float t = a0 * W1[f] + a1 * W1[32 + f] + a2 * W1[64 + f];
        float h1 = fmaxf(d * t + b1[f], 0.0f);
        float o = 0.0f;
#pragma unroll
        for (int k = 0; k < 32; ++k)
            o += __shfl(h1, k, 32) * W2[k * 32 + f];
        hs2[(size_t)col * 32 + f] = d * o;
    }
}

// ---------------- fused layer 2 + layer-3 transform: agg32 -> ReLU -> W3 -> hs3 ----------------
__global__ void k_L2(const unsigned int* __restrict__ pairs, const int* __restrict__ bbase,
                     const float* __restrict__ hs2, const float* __restrict__ dinv,
                     const float* __restrict__ b2, const float* __restrict__ W3,
                     float* __restrict__ hs3, int n) {
    __shared__ double acc[256 * 32];            // 64 KB
    int b = blockIdx.x;
    for (int i = threadIdx.x; i < 256 * 32; i += blockDim.x) acc[i] = 0.0;
    __syncthreads();
    int s = bbase[b], e = bbase[b + 1];
    int f = threadIdx.x & 31;
    int g = threadIdx.x >> 5;                   // 16 groups of 32 (512 threads)
    for (int j = s + g; j < e; j += 16) {
        unsigned pk = pairs[j];                 // broadcast within group
        int r = (int)(pk >> 8);
        int cl = (int)(pk & 255u);
        float v = hs2[(size_t)r * 32 + f];      // coalesced 128B gather (LLC)
        atomicAdd(&acc[cl * 32 + f], (double)v);
    }
    __syncthreads();
    for (int ci = g; ci < 256; ci += 16) {
        int col = (b << 8) + ci;
        if (col >= n) continue;
        float d = dinv[col];
        float h2 = fmaxf(d * ((float)acc[ci * 32 + f] + hs2[(size_t)col * 32 + f]) + b2[f], 0.0f);
        float w = h2 * W3[f];
        for (int off = 16; off > 0; off >>= 1) w += __shfl_down(w, off, 32);
        if (f == 0) hs3[col] = d * w;
    }
}

// ---------------- layer 3 aggregate: scalar, hs3 is 1MB L2-resident ----------------
__global__ void k_L3(const unsigned int* __restrict__ pairs, const int* __restrict__ bbase,
                     const float* __restrict__ hs3, const float* __restrict__ dinv,
                     const float* __restrict__ b3, float* __restrict__ out, int n) {
    __shared__ double acc[256];
    int b = blockIdx.x;
    acc[threadIdx.x] = 0.0;
    __syncthreads();
    int s = bbase[b], e = bbase[b + 1];
    for (int j = s + threadIdx.x; j < e; j += blockDim.x) {
        unsigned pk = pairs[j];
        atomicAdd(&acc[pk & 255u], (double)hs3[pk >> 8]);
    }
    __syncthreads();
    int col = (b << 8) + threadIdx.x;
    if (col < n) out[col] = dinv[col] * ((float)acc[threadIdx.x] + hs3[col]) + b3[0];
}

// ---------------- launch ----------------

extern "C" void kernel_launch(void* const* d_in, const int* in_sizes, int n_in,
                              void* d_out, int out_size, void* d_ws, size_t ws_size,
                              hipStream_t stream) {
    const float* x  = (const float*)d_in[0];
    const float* y1 = (const float*)d_in[1];
    const int*   ei = (const int*)d_in[2];
    const float* W1 = (const float*)d_in[3];
    const float* b1 = (const float*)d_in[4];
    const float* W2 = (const float*)d_in[5];
    const float* b2 = (const float*)d_in[6];
    const float* W3 = (const float*)d_in[7];
    const float* b3 = (const float*)d_in[8];
    float* out = (float*)d_out;

    const int n = in_sizes[1];          // 250000
    const int E = in_sizes[2] / 2;      // 8000000
    const int nbuk = (n + 255) >> 8;    // 977

    char* ws = (char*)d_ws;
    size_t off = 0;
    auto alloc = [&](size_t bytes) { char* p = ws + off; off += (bytes + 255) & ~(size_t)255; return p; };
    unsigned int* pairs = (unsigned int*)alloc((size_t)E * sizeof(unsigned int)); // 32MB
    float*  hs2   = (float*)alloc((size_t)n * 32 * sizeof(float));               // 32MB
    float4* s4    = (float4*)alloc((size_t)n * sizeof(float4));                  // 4MB
    float*  dinv  = (float*)alloc((size_t)n * sizeof(float));
    float*  hs3   = (float*)alloc((size_t)n * sizeof(float));
    int*    bcnt  = (int*)alloc((size_t)nbuk * sizeof(int));
    int*    bbase = (int*)alloc((size_t)(nbuk + 1) * sizeof(int));
    int*    cursor= (int*)alloc((size_t)nbuk * sizeof(int));
    (void)ws_size;

    // bucket CSR-lite build
    hipMemsetAsync(bcnt, 0, (size_t)nbuk * sizeof(int), stream);
    k_hist<<<256, 256, 0, stream>>>(ei, E, nbuk, bcnt);
    k_scan<<<1, 1024, 0, stream>>>(bcnt, nbuk, E, bbase, cursor);
    const int nbin = 480;
    const int chunk = (E + nbin - 1) / nbin;
    k_bin<<<nbin, 256, 0, stream>>>(ei, E, nbuk, chunk, cursor, pairs);

    // degree -> dinv -> s4
    k_dcnt<<<nbuk, 256, 0, stream>>>(pairs, bbase, n, dinv);
    k_s4<<<(n + 255) / 256, 256, 0, stream>>>(x, y1, dinv, s4, n);

    // fused layers
    k_L1<<<nbuk, 256, 0, stream>>>(pairs, bbase, s4, W1, b1, W2, hs2, n);
    k_L2<<<nbuk, 512, 0, stream>>>(pairs, bbase, hs2, dinv, b2, W3, hs3, n);
    k_L3<<<nbuk, 256, 0, stream>>>(pairs, bbase, hs3, dinv, b3, out, n);
}

// Round 8
// 453.632 us; speedup vs baseline: 5.6773x; 2.0051x over previous
//
#include <hip/hip_runtime.h>
#include <stdint.h>

#define BSH 7           // bucket shift: 128 cols per bucket
#define BW  128         // bucket width
#define MAXBUK 2048     // >= ceil(250000/128) = 1954

// ---------------- bucket histogram (col >> BSH) ----------------
__global__ void k_hist(const int* __restrict__ ei, int E, int nbuk, int* __restrict__ bcnt) {
    __shared__ int h[MAXBUK];
    for (int b = threadIdx.x; b < nbuk; b += blockDim.x) h[b] = 0;
    __syncthreads();
    int stride = gridDim.x * blockDim.x;
    for (int e = blockIdx.x * blockDim.x + threadIdx.x; e < E; e += stride)
        atomicAdd(&h[ei[E + e] >> BSH], 1);
    __syncthreads();
    for (int b = threadIdx.x; b < nbuk; b += blockDim.x)
        if (h[b]) atomicAdd(&bcnt[b], h[b]);
}

// ---------------- exclusive scan of bucket counts (nbuk <= 2048) ----------------
__global__ void k_scan(const int* __restrict__ bcnt, int nbuk, int E,
                       int* __restrict__ bbase, int* __restrict__ cursor) {
    __shared__ int s0[MAXBUK], s1[MAXBUK];
    int tid = threadIdx.x;
    for (int i = tid; i < MAXBUK; i += blockDim.x) s0[i] = (i < nbuk) ? bcnt[i] : 0;
    __syncthreads();
    int* src = s0; int* dst = s1;
    for (int off = 1; off < MAXBUK; off <<= 1) {
        for (int i = tid; i < MAXBUK; i += blockDim.x)
            dst[i] = src[i] + ((i >= off) ? src[i - off] : 0);
        __syncthreads();
        int* t = src; src = dst; dst = t;
    }
    for (int i = tid; i < nbuk; i += blockDim.x) {
        int excl = src[i] - bcnt[i];
        bbase[i] = excl;
        cursor[i] = excl;
    }
    if (tid == 0) bbase[nbuk] = E;
}

// ---------------- block-reservation binning ----------------
// pairs[pos] = (row << BSH) | (col & (BW-1)), grouped by bucket. Order within a
// bucket is non-deterministic; all consumers accumulate in f64 (order-insensitive).
__global__ void k_bin(const int* __restrict__ ei, int E, int nbuk, int chunk,
                      int* __restrict__ cursor, unsigned int* __restrict__ pairs) {
    __shared__ int h[MAXBUK];
    __shared__ int base[MAXBUK];
    int start = (int)blockIdx.x * chunk;
    int end = min(start + chunk, E);
    for (int b = threadIdx.x; b < nbuk; b += blockDim.x) h[b] = 0;
    __syncthreads();
    for (int i = start + threadIdx.x; i < end; i += blockDim.x)
        atomicAdd(&h[ei[E + i] >> BSH], 1);
    __syncthreads();
    for (int b = threadIdx.x; b < nbuk; b += blockDim.x) {
        int c = h[b];
        base[b] = c ? atomicAdd(&cursor[b], c) : 0;
        h[b] = 0;                      // reuse as local cursor
    }
    __syncthreads();
    for (int i = start + threadIdx.x; i < end; i += blockDim.x) {
        int r = ei[i];
        int c = ei[E + i];
        int b = c >> BSH;
        int loc = atomicAdd(&h[b], 1);
        pairs[base[b] + loc] = ((unsigned)r << BSH) | (unsigned)(c & (BW - 1));
    }
}

// ---------------- per-bucket degree count -> dinv ----------------
__global__ void k_dcnt(const unsigned int* __restrict__ pairs, const int* __restrict__ bbase,
                       int n, float* __restrict__ dinv) {
    __shared__ int cnt[BW];
    int b = blockIdx.x;
    if (threadIdx.x < BW) cnt[threadIdx.x] = 0;
    __syncthreads();
    int s = bbase[b], e = bbase[b + 1];
    for (int j = s + threadIdx.x; j < e; j += blockDim.x)
        atomicAdd(&cnt[pairs[j] & (BW - 1u)], 1);
    __syncthreads();
    int col = (b << BSH) + threadIdx.x;
    if (threadIdx.x < BW && col < n)
        dinv[col] = rsqrtf((float)cnt[threadIdx.x] + 1.0f);
}

// ---------------- s4 table: (dinv*x0, dinv*x1, dinv*y1, dinv) ----------------
__global__ void k_s4(const float* __restrict__ x, const float* __restrict__ y1,
                     const float* __restrict__ dinv, float4* __restrict__ s4, int n) {
    int v = blockIdx.x * blockDim.x + threadIdx.x;
    if (v >= n) return;
    float d = dinv[v];
    s4[v] = make_float4(d * x[2 * v], d * x[2 * v + 1], d * y1[v], d);
}

// ---------------- fused layer 1: agg3 -> W1+ReLU -> W2*dinv -> hs2 ----------------
__global__ void k_L1(const unsigned int* __restrict__ pairs, const int* __restrict__ bbase,
                     const float4* __restrict__ s4, const float* __restrict__ W1,
                     const float* __restrict__ b1, const float* __restrict__ W2,
                     float* __restrict__ hs2, int n) {
    __shared__ double acc[BW * 3];
    int b = blockIdx.x;
    for (int i = threadIdx.x; i < BW * 3; i += blockDim.x) acc[i] = 0.0;
    __syncthreads();
    int s = bbase[b], e = bbase[b + 1];
    int j = s + threadIdx.x * 2;
    int stride = blockDim.x * 2;
    for (; j + 1 < e; j += stride) {
        unsigned pk0 = pairs[j], pk1 = pairs[j + 1];
        float4 v0 = s4[pk0 >> BSH];             // independent 16B gathers (L2-resident)
        float4 v1 = s4[pk1 >> BSH];
        int c0 = (int)(pk0 & (BW - 1u)) * 3, c1 = (int)(pk1 & (BW - 1u)) * 3;
        atomicAdd(&acc[c0 + 0], (double)v0.x);
        atomicAdd(&acc[c0 + 1], (double)v0.y);
        atomicAdd(&acc[c0 + 2], (double)v0.z);
        atomicAdd(&acc[c1 + 0], (double)v1.x);
        atomicAdd(&acc[c1 + 1], (double)v1.y);
        atomicAdd(&acc[c1 + 2], (double)v1.z);
    }
    if (j < e) {
        unsigned pk = pairs[j];
        float4 v = s4[pk >> BSH];
        int c = (int)(pk & (BW - 1u)) * 3;
        atomicAdd(&acc[c + 0], (double)v.x);
        atomicAdd(&acc[c + 1], (double)v.y);
        atomicAdd(&acc[c + 2], (double)v.z);
    }
    __syncthreads();
    int f = threadIdx.x & 31;
    int g = threadIdx.x >> 5;                   // 8 groups of 32
    for (int ci = g; ci < BW; ci += 8) {
        int col = (b << BSH) + ci;
        if (col >= n) continue;                 // group-uniform
        float4 sc = s4[col];
        float a0 = (float)acc[ci * 3 + 0] + sc.x;   // + self loop
        float a1 = (float)acc[ci * 3 + 1] + sc.y;
        float a2 = (float)acc[ci * 3 + 2] + sc.z;
        float d = sc.w;
        float t = a0 * W1[f] + a1 * W1[32 + f] + a2 * W1[64 + f];
        float h1 = fmaxf(d * t + b1[f], 0.0f);
        float o = 0.0f;
#pragma unroll
        for (int k = 0; k < 32; ++k)
            o += __shfl(h1, k, 32) * W2[k * 32 + f];
        hs2[(size_t)col * 32 + f] = d * o;
    }
}

// ---------------- fused layer 2 + layer-3 transform: agg32 -> ReLU -> W3 -> hs3 ----------------
__global__ void k_L2(const unsigned int* __restrict__ pairs, const int* __restrict__ bbase,
                     const float* __restrict__ hs2, const float* __restrict__ dinv,
                     const float* __restrict__ b2, const float* __restrict__ W3,
                     float* __restrict__ hs3, int n) {
    __shared__ double acc[BW * 32];             // 32 KB -> 4 blocks/CU
    int b = blockIdx.x;
    for (int i = threadIdx.x; i < BW * 32; i += blockDim.x) acc[i] = 0.0;
    __syncthreads();
    int s = bbase[b], e = bbase[b + 1];
    int f = threadIdx.x & 31;
    int g = threadIdx.x >> 5;                   // 16 groups of 32 (512 threads)
    int j = s + (g << 2);
    for (; j + 3 < e; j += 64) {                // 4-deep MLP per group
        unsigned pk0 = pairs[j], pk1 = pairs[j + 1], pk2 = pairs[j + 2], pk3 = pairs[j + 3];
        float v0 = hs2[(size_t)(pk0 >> BSH) * 32 + f];   // 4 independent 128B gathers
        float v1 = hs2[(size_t)(pk1 >> BSH) * 32 + f];
        float v2 = hs2[(size_t)(pk2 >> BSH) * 32 + f];
        float v3 = hs2[(size_t)(pk3 >> BSH) * 32 + f];
        atomicAdd(&acc[(pk0 & (BW - 1u)) * 32 + f], (double)v0);
        atomicAdd(&acc[(pk1 & (BW - 1u)) * 32 + f], (double)v1);
        atomicAdd(&acc[(pk2 & (BW - 1u)) * 32 + f], (double)v2);
        atomicAdd(&acc[(pk3 & (BW - 1u)) * 32 + f], (double)v3);
    }
    if (j < e) {
        int lim = min(j + 4, e);
        for (int t = j; t < lim; ++t) {
            unsigned pk = pairs[t];
            float v = hs2[(size_t)(pk >> BSH) * 32 + f];
            atomicAdd(&acc[(pk & (BW - 1u)) * 32 + f], (double)v);
        }
    }
    __syncthreads();
    for (int ci = g; ci < BW; ci += 16) {
        int col = (b << BSH) + ci;
        if (col >= n) continue;
        float d = dinv[col];
        float h2 = fmaxf(d * ((float)acc[ci * 32 + f] + hs2[(size_t)col * 32 + f]) + b2[f], 0.0f);
        float w = h2 * W3[f];
        for (int off = 16; off > 0; off >>= 1) w += __shfl_down(w, off, 32);
        if (f == 0) hs3[col] = d * w;
    }
}

// ---------------- layer 3 aggregate: scalar, hs3 is 1MB L2-resident ----------------
__global__ void k_L3(const unsigned int* __restrict__ pairs, const int* __restrict__ bbase,
                     const float* __restrict__ hs3, const float* __restrict__ dinv,
                     const float* __restrict__ b3, float* __restrict__ out, int n) {
    __shared__ double acc[BW];
    int b = blockIdx.x;
    if (threadIdx.x < BW) acc[threadIdx.x] = 0.0;
    __syncthreads();
    int s = bbase[b], e = bbase[b + 1];
    int j = s + threadIdx.x * 4;
    int stride = blockDim.x * 4;
    for (; j + 3 < e; j += stride) {
        unsigned pk0 = pairs[j], pk1 = pairs[j + 1], pk2 = pairs[j + 2], pk3 = pairs[j + 3];
        float v0 = hs3[pk0 >> BSH];
        float v1 = hs3[pk1 >> BSH];
        float v2 = hs3[pk2 >> BSH];
        float v3 = hs3[pk3 >> BSH];
        atomicAdd(&acc[pk0 & (BW - 1u)], (double)v0);
        atomicAdd(&acc[pk1 & (BW - 1u)], (double)v1);
        atomicAdd(&acc[pk2 & (BW - 1u)], (double)v2);
        atomicAdd(&acc[pk3 & (BW - 1u)], (double)v3);
    }
    if (j < e) {
        int lim = min(j + 4, e);
        for (int t = j; t < lim; ++t) {
            unsigned pk = pairs[t];
            atomicAdd(&acc[pk & (BW - 1u)], (double)hs3[pk >> BSH]);
        }
    }
    __syncthreads();
    int col = (b << BSH) + threadIdx.x;
    if (threadIdx.x < BW && col < n)
        out[col] = dinv[col] * ((float)acc[threadIdx.x] + hs3[col]) + b3[0];
}

// ---------------- launch ----------------

extern "C" void kernel_launch(void* const* d_in, const int* in_sizes, int n_in,
                              void* d_out, int out_size, void* d_ws, size_t ws_size,
                              hipStream_t stream) {
    const float* x  = (const float*)d_in[0];
    const float* y1 = (const float*)d_in[1];
    const int*   ei = (const int*)d_in[2];
    const float* W1 = (const float*)d_in[3];
    const float* b1 = (const float*)d_in[4];
    const float* W2 = (const float*)d_in[5];
    const float* b2 = (const float*)d_in[6];
    const float* W3 = (const float*)d_in[7];
    const float* b3 = (const float*)d_in[8];
    float* out = (float*)d_out;

    const int n = in_sizes[1];          // 250000
    const int E = in_sizes[2] / 2;      // 8000000
    const int nbuk = (n + BW - 1) >> BSH;   // 1954

    char* ws = (char*)d_ws;
    size_t off = 0;
    auto alloc = [&](size_t bytes) { char* p = ws + off; off += (bytes + 255) & ~(size_t)255; return p; };
    unsigned int* pairs = (unsigned int*)alloc((size_t)E * sizeof(unsigned int)); // 32MB
    float*  hs2   = (float*)alloc((size_t)n * 32 * sizeof(float));               // 32MB
    float4* s4    = (float4*)alloc((size_t)n * sizeof(float4));                  // 4MB
    float*  dinv  = (float*)alloc((size_t)n * sizeof(float));
    float*  hs3   = (float*)alloc((size_t)n * sizeof(float));
    int*    bcnt  = (int*)alloc((size_t)nbuk * sizeof(int));
    int*    bbase = (int*)alloc((size_t)(nbuk + 1) * sizeof(int));
    int*    cursor= (int*)alloc((size_t)nbuk * sizeof(int));
    (void)ws_size;

    // bucket CSR-lite build
    hipMemsetAsync(bcnt, 0, (size_t)nbuk * sizeof(int), stream);
    k_hist<<<256, 256, 0, stream>>>(ei, E, nbuk, bcnt);
    k_scan<<<1, 1024, 0, stream>>>(bcnt, nbuk, E, bbase, cursor);
    const int nbin = 480;
    const int chunk = (E + nbin - 1) / nbin;
    k_bin<<<nbin, 256, 0, stream>>>(ei, E, nbuk, chunk, cursor, pairs);

    // degree -> dinv -> s4
    k_dcnt<<<nbuk, 128, 0, stream>>>(pairs, bbase, n, dinv);
    k_s4<<<(n + 255) / 256, 256, 0, stream>>>(x, y1, dinv, s4, n);

    // fused layers
    k_L1<<<nbuk, 256, 0, stream>>>(pairs, bbase, s4, W1, b1, W2, hs2, n);
    k_L2<<<nbuk, 512, 0, stream>>>(pairs, bbase, hs2, dinv, b2, W3, hs3, n);
    k_L3<<<nbuk, 256, 0, stream>>>(pairs, bbase, hs3, dinv, b3, out, n);
}

// Round 9
// 429.728 us; speedup vs baseline: 5.9931x; 1.0556x over previous
//
#include <hip/hip_runtime.h>
#include <stdint.h>

#define BSH 7           // fine bucket shift: 128 cols per bucket
#define BW  128         // fine bucket width
#define MAXBUK 2048     // >= ceil(250000/128) = 1954
#define SSH 13          // superbucket shift: 8192 cols
#define SBW 8192
#define MAXSB 64        // >= ceil(1954/64) = 31 superbuckets (+1 for end)

// ---------------- fine histogram (col >> BSH) ----------------
__global__ void k_hist(const int* __restrict__ ei, int E, int nbuk, int* __restrict__ bcnt) {
    __shared__ int h[MAXBUK];
    for (int b = threadIdx.x; b < nbuk; b += blockDim.x) h[b] = 0;
    __syncthreads();
    int stride = gridDim.x * blockDim.x;
    for (int e = blockIdx.x * blockDim.x + threadIdx.x; e < E; e += stride)
        atomicAdd(&h[ei[E + e] >> BSH], 1);
    __syncthreads();
    for (int b = threadIdx.x; b < nbuk; b += blockDim.x)
        if (h[b]) atomicAdd(&bcnt[b], h[b]);
}

// ---------------- exclusive scan of fine counts + superbucket bases ----------------
__global__ void k_scan(const int* __restrict__ bcnt, int nbuk, int E, int nsb,
                       int* __restrict__ bbase, int* __restrict__ cursor,
                       int* __restrict__ sbase, int* __restrict__ scursor) {
    __shared__ int s0[MAXBUK], s1[MAXBUK];
    int tid = threadIdx.x;
    for (int i = tid; i < MAXBUK; i += blockDim.x) s0[i] = (i < nbuk) ? bcnt[i] : 0;
    __syncthreads();
    int* src = s0; int* dst = s1;
    for (int off = 1; off < MAXBUK; off <<= 1) {
        for (int i = tid; i < MAXBUK; i += blockDim.x)
            dst[i] = src[i] + ((i >= off) ? src[i - off] : 0);
        __syncthreads();
        int* t = src; src = dst; dst = t;
    }
    // src[] now holds the inclusive scan
    for (int i = tid; i < nbuk; i += blockDim.x) {
        int excl = src[i] - bcnt[i];
        bbase[i] = excl;
        cursor[i] = excl;
    }
    if (tid == 0) bbase[nbuk] = E;
    for (int i = tid; i <= nsb; i += blockDim.x) {
        int idx = i << 6;                       // first fine bucket of superbucket i
        int v = (idx < nbuk) ? (src[idx] - bcnt[idx]) : E;
        sbase[i] = v;
        if (i < nsb) scursor[i] = v;
    }
}

// ---------------- pass 1: bin into 31 superbuckets (2KB runs) ----------------
// tmp[pos] = (row << SSH) | (col & (SBW-1))
__global__ void k_bin1(const int* __restrict__ ei, int E, int chunk,
                       int* __restrict__ scursor, unsigned int* __restrict__ tmp) {
    __shared__ int h[MAXSB], base[MAXSB];
    int start = (int)blockIdx.x * chunk;
    int end = min(start + chunk, E);
    if (threadIdx.x < MAXSB) h[threadIdx.x] = 0;
    __syncthreads();
    for (int i = start + threadIdx.x; i < end; i += blockDim.x)
        atomicAdd(&h[ei[E + i] >> SSH], 1);
    __syncthreads();
    if (threadIdx.x < MAXSB) {
        int c = h[threadIdx.x];
        base[threadIdx.x] = c ? atomicAdd(&scursor[threadIdx.x], c) : 0;
        h[threadIdx.x] = 0;                     // reuse as local cursor
    }
    __syncthreads();
    for (int i = start + threadIdx.x; i < end; i += blockDim.x) {
        int r = ei[i];
        int c = ei[E + i];
        int sb = c >> SSH;
        int loc = atomicAdd(&h[sb], 1);
        tmp[base[sb] + loc] = ((unsigned)r << SSH) | (unsigned)(c & (SBW - 1));
    }
}

// ---------------- pass 2: refine each superbucket into 64 fine buckets (1KB runs) ----------------
// pairs[pos] = (row << BSH) | (col & (BW-1)), grouped by fine bucket. Order within a
// bucket is non-deterministic; all consumers accumulate in f64 (order-insensitive).
__global__ void k_bin2(const unsigned int* __restrict__ tmp, const int* __restrict__ sbase,
                       int* __restrict__ cursor, unsigned int* __restrict__ pairs) {
    __shared__ int h[64], base[64];
    int sb = blockIdx.x;
    int s = sbase[sb], e = sbase[sb + 1];
    int cnt = e - s;
    int chunk = (cnt + gridDim.y - 1) / gridDim.y;
    int start = s + (int)blockIdx.y * chunk;
    int end = min(start + chunk, e);
    if (threadIdx.x < 64) h[threadIdx.x] = 0;
    __syncthreads();
    for (int i = start + threadIdx.x; i < end; i += blockDim.x)
        atomicAdd(&h[(tmp[i] & (SBW - 1u)) >> BSH], 1);
    __syncthreads();
    if (threadIdx.x < 64) {
        int c = h[threadIdx.x];
        int fine = (sb << 6) + threadIdx.x;
        base[threadIdx.x] = c ? atomicAdd(&cursor[fine], c) : 0;
        h[threadIdx.x] = 0;                     // reuse as local cursor
    }
    __syncthreads();
    for (int i = start + threadIdx.x; i < end; i += blockDim.x) {
        unsigned v = tmp[i];
        unsigned r = v >> SSH;
        unsigned colLow = v & (SBW - 1u);
        int lb = (int)(colLow >> BSH);
        int loc = atomicAdd(&h[lb], 1);
        pairs[base[lb] + loc] = (r << BSH) | (colLow & (BW - 1u));
    }
}

// ---------------- per-bucket degree count -> dinv ----------------
__global__ void k_dcnt(const unsigned int* __restrict__ pairs, const int* __restrict__ bbase,
                       int n, float* __restrict__ dinv) {
    __shared__ int cnt[BW];
    int b = blockIdx.x;
    if (threadIdx.x < BW) cnt[threadIdx.x] = 0;
    __syncthreads();
    int s = bbase[b], e = bbase[b + 1];
    for (int j = s + threadIdx.x; j < e; j += blockDim.x)
        atomicAdd(&cnt[pairs[j] & (BW - 1u)], 1);
    __syncthreads();
    int col = (b << BSH) + threadIdx.x;
    if (threadIdx.x < BW && col < n)
        dinv[col] = rsqrtf((float)cnt[threadIdx.x] + 1.0f);
}

// ---------------- s4 table: (dinv*x0, dinv*x1, dinv*y1, dinv) ----------------
__global__ void k_s4(const float* __restrict__ x, const float* __restrict__ y1,
                     const float* __restrict__ dinv, float4* __restrict__ s4, int n) {
    int v = blockIdx.x * blockDim.x + threadIdx.x;
    if (v >= n) return;
    float d = dinv[v];
    s4[v] = make_float4(d * x[2 * v], d * x[2 * v + 1], d * y1[v], d);
}

// ---------------- fused layer 1: agg3 -> W1+ReLU -> W2*dinv -> hs2 ----------------
__global__ void k_L1(const unsigned int* __restrict__ pairs, const int* __restrict__ bbase,
                     const float4* __restrict__ s4, const float* __restrict__ W1,
                     const float* __restrict__ b1, const float* __restrict__ W2,
                     float* __restrict__ hs2, int n) {
    __shared__ double acc[BW * 3];
    int b = blockIdx.x;
    for (int i = threadIdx.x; i < BW * 3; i += blockDim.x) acc[i] = 0.0;
    __syncthreads();
    int s = bbase[b], e = bbase[b + 1];
    int j = s + threadIdx.x * 2;
    int stride = blockDim.x * 2;
    for (; j + 1 < e; j += stride) {
        unsigned pk0 = pairs[j], pk1 = pairs[j + 1];
        float4 v0 = s4[pk0 >> BSH];             // independent 16B gathers (L2-resident)
        float4 v1 = s4[pk1 >> BSH];
        int c0 = (int)(pk0 & (BW - 1u)) * 3, c1 = (int)(pk1 & (BW - 1u)) * 3;
        atomicAdd(&acc[c0 + 0], (double)v0.x);
        atomicAdd(&acc[c0 + 1], (double)v0.y);
        atomicAdd(&acc[c0 + 2], (double)v0.z);
        atomicAdd(&acc[c1 + 0], (double)v1.x);
        atomicAdd(&acc[c1 + 1], (double)v1.y);
        atomicAdd(&acc[c1 + 2], (double)v1.z);
    }
    if (j < e) {
        unsigned pk = pairs[j];
        float4 v = s4[pk >> BSH];
        int c = (int)(pk & (BW - 1u)) * 3;
        atomicAdd(&acc[c + 0], (double)v.x);
        atomicAdd(&acc[c + 1], (double)v.y);
        atomicAdd(&acc[c + 2], (double)v.z);
    }
    __syncthreads();
    int f = threadIdx.x & 31;
    int g = threadIdx.x >> 5;                   // 8 groups of 32
    for (int ci = g; ci < BW; ci += 8) {
        int col = (b << BSH) + ci;
        if (col >= n) continue;                 // group-uniform
        float4 sc = s4[col];
        float a0 = (float)acc[ci * 3 + 0] + sc.x;   // + self loop
        float a1 = (float)acc[ci * 3 + 1] + sc.y;
        float a2 = (float)acc[ci * 3 + 2] + sc.z;
        float d = sc.w;
        float t = a0 * W1[f] + a1 * W1[32 + f] + a2 * W1[64 + f];
        float h1 = fmaxf(d * t + b1[f], 0.0f);
        float o = 0.0f;
#pragma unroll
        for (int k = 0; k < 32; ++k)
            o += __shfl(h1, k, 32) * W2[k * 32 + f];
        hs2[(size_t)col * 32 + f] = d * o;
    }
}

// ---------------- fused layer 2 + layer-3 transform: agg32 -> ReLU -> W3 -> hs3 ----------------
__global__ void k_L2(const unsigned int* __restrict__ pairs, const int* __restrict__ bbase,
                     const float* __restrict__ hs2, const float* __restrict__ dinv,
                     const float* __restrict__ b2, const float* __restrict__ W3,
                     float* __restrict__ hs3, int n) {
    __shared__ double acc[BW * 32];             // 32 KB -> 4 blocks/CU
    int b = blockIdx.x;
    for (int i = threadIdx.x; i < BW * 32; i += blockDim.x) acc[i] = 0.0;
    __syncthreads();
    int s = bbase[b], e = bbase[b + 1];
    int f = threadIdx.x & 31;
    int g = threadIdx.x >> 5;                   // 16 groups of 32 (512 threads)
    int j = s + (g << 2);
    for (; j + 3 < e; j += 64) {                // 4-deep MLP per group
        unsigned pk0 = pairs[j], pk1 = pairs[j + 1], pk2 = pairs[j + 2], pk3 = pairs[j + 3];
        float v0 = hs2[(size_t)(pk0 >> BSH) * 32 + f];   // 4 independent 128B gathers
        float v1 = hs2[(size_t)(pk1 >> BSH) * 32 + f];
        float v2 = hs2[(size_t)(pk2 >> BSH) * 32 + f];
        float v3 = hs2[(size_t)(pk3 >> BSH) * 32 + f];
        atomicAdd(&acc[(pk0 & (BW - 1u)) * 32 + f], (double)v0);
        atomicAdd(&acc[(pk1 & (BW - 1u)) * 32 + f], (double)v1);
        atomicAdd(&acc[(pk2 & (BW - 1u)) * 32 + f], (double)v2);
        atomicAdd(&acc[(pk3 & (BW - 1u)) * 32 + f], (double)v3);
    }
    if (j < e) {
        int lim = min(j + 4, e);
        for (int t = j; t < lim; ++t) {
            unsigned pk = pairs[t];
            float v = hs2[(size_t)(pk >> BSH) * 32 + f];
            atomicAdd(&acc[(pk & (BW - 1u)) * 32 + f], (double)v);
        }
    }
    __syncthreads();
    for (int ci = g; ci < BW; ci += 16) {
        int col = (b << BSH) + ci;
        if (col >= n) continue;
        float d = dinv[col];
        float h2 = fmaxf(d * ((float)acc[ci * 32 + f] + hs2[(size_t)col * 32 + f]) + b2[f], 0.0f);
        float w = h2 * W3[f];
        for (int off = 16; off > 0; off >>= 1) w += __shfl_down(w, off, 32);
        if (f == 0) hs3[col] = d * w;
    }
}

// ---------------- layer 3 aggregate: scalar, hs3 is 1MB L2-resident ----------------
__global__ void k_L3(const unsigned int* __restrict__ pairs, const int* __restrict__ bbase,
                     const float* __restrict__ hs3, const float* __restrict__ dinv,
                     const float* __restrict__ b3, float* __restrict__ out, int n) {
    __shared__ double acc[BW];
    int b = blockIdx.x;
    if (threadIdx.x < BW) acc[threadIdx.x] = 0.0;
    __syncthreads();
    int s = bbase[b], e = bbase[b + 1];
    int j = s + threadIdx.x * 4;
    int stride = blockDim.x * 4;
    for (; j + 3 < e; j += stride) {
        unsigned pk0 = pairs[j], pk1 = pairs[j + 1], pk2 = pairs[j + 2], pk3 = pairs[j + 3];
        float v0 = hs3[pk0 >> BSH];
        float v1 = hs3[pk1 >> BSH];
        float v2 = hs3[pk2 >> BSH];
        float v3 = hs3[pk3 >> BSH];
        atomicAdd(&acc[pk0 & (BW - 1u)], (double)v0);
        atomicAdd(&acc[pk1 & (BW - 1u)], (double)v1);
        atomicAdd(&acc[pk2 & (BW - 1u)], (double)v2);
        atomicAdd(&acc[pk3 & (BW - 1u)], (double)v3);
    }
    if (j < e) {
        int lim = min(j + 4, e);
        for (int t = j; t < lim; ++t) {
            unsigned pk = pairs[t];
            atomicAdd(&acc[pk & (BW - 1u)], (double)hs3[pk >> BSH]);
        }
    }
    __syncthreads();
    int col = (b << BSH) + threadIdx.x;
    if (threadIdx.x < BW && col < n)
        out[col] = dinv[col] * ((float)acc[threadIdx.x] + hs3[col]) + b3[0];
}

// ---------------- launch ----------------

extern "C" void kernel_launch(void* const* d_in, const int* in_sizes, int n_in,
                              void* d_out, int out_size, void* d_ws, size_t ws_size,
                              hipStream_t stream) {
    const float* x  = (const float*)d_in[0];
    const float* y1 = (const float*)d_in[1];
    const int*   ei = (const int*)d_in[2];
    const float* W1 = (const float*)d_in[3];
    const float* b1 = (const float*)d_in[4];
    const float* W2 = (const float*)d_in[5];
    const float* b2 = (const float*)d_in[6];
    const float* W3 = (const float*)d_in[7];
    const float* b3 = (const float*)d_in[8];
    float* out = (float*)d_out;

    const int n = in_sizes[1];          // 250000
    const int E = in_sizes[2] / 2;      // 8000000
    const int nbuk = (n + BW - 1) >> BSH;   // 1954
    const int nsb = (nbuk + 63) >> 6;       // 31 superbuckets

    char* ws = (char*)d_ws;
    size_t off = 0;
    auto alloc = [&](size_t bytes) { char* p = ws + off; off += (bytes + 255) & ~(size_t)255; return p; };
    unsigned int* pairs = (unsigned int*)alloc((size_t)E * sizeof(unsigned int)); // 32MB
    float*  hs2   = (float*)alloc((size_t)n * 32 * sizeof(float));               // 32MB
    float4* s4    = (float4*)alloc((size_t)n * sizeof(float4));                  // 4MB
    float*  dinv  = (float*)alloc((size_t)n * sizeof(float));
    float*  hs3   = (float*)alloc((size_t)n * sizeof(float));
    int*    bcnt  = (int*)alloc((size_t)nbuk * sizeof(int));
    int*    bbase = (int*)alloc((size_t)(nbuk + 1) * sizeof(int));
    int*    cursor= (int*)alloc((size_t)nbuk * sizeof(int));
    int*    sbase = (int*)alloc((size_t)(nsb + 1) * sizeof(int));
    int*    scursor = (int*)alloc((size_t)nsb * sizeof(int));
    (void)ws_size;
    // tmp (pass-1 output) aliases hs2: tmp is dead before k_L1 writes hs2,
    // and E*4 bytes == n*32*4 bytes (both 32MB).
    unsigned int* tmp = (unsigned int*)hs2;

    // fine histogram + scans
    hipMemsetAsync(bcnt, 0, (size_t)nbuk * sizeof(int), stream);
    k_hist<<<256, 256, 0, stream>>>(ei, E, nbuk, bcnt);
    k_scan<<<1, 1024, 0, stream>>>(bcnt, nbuk, E, nsb, bbase, cursor, sbase, scursor);

    // two-pass radix partition
    const int nbin1 = 512;
    const int chunk1 = (E + nbin1 - 1) / nbin1;
    k_bin1<<<nbin1, 256, 0, stream>>>(ei, E, chunk1, scursor, tmp);
    k_bin2<<<dim3(nsb, 16), 256, 0, stream>>>(tmp, sbase, cursor, pairs);

    // degree -> dinv -> s4
    k_dcnt<<<nbuk, 128, 0, stream>>>(pairs, bbase, n, dinv);
    k_s4<<<(n + 255) / 256, 256, 0, stream>>>(x, y1, dinv, s4, n);

    // fused layers
    k_L1<<<nbuk, 256, 0, stream>>>(pairs, bbase, s4, W1, b1, W2, hs2, n);
    k_L2<<<nbuk, 512, 0, stream>>>(pairs, bbase, hs2, dinv, b2, W3, hs3, n);
    k_L3<<<nbuk, 256, 0, stream>>>(pairs, bbase, hs3, dinv, b3, out, n);
}

// Round 11
// 406.454 us; speedup vs baseline: 6.3363x; 1.0573x over previous
//
#include <hip/hip_runtime.h>
#include <stdint.h>

#define BSH 7           // fine bucket shift: 128 cols per bucket
#define BW  128         // fine bucket width
#define MAXBUK 2048     // >= ceil(250000/128) = 1954
#define SSH 13          // superbucket shift: 8192 cols
#define SBW 8192
#define MAXSB 64        // >= 31 superbuckets
#define CMAX 4096       // LDS edge-cache per binning block

// ---------------- fine histogram (col >> BSH) ----------------
__global__ void k_hist(const int* __restrict__ ei, int E, int nbuk, int* __restrict__ bcnt) {
    __shared__ int h[MAXBUK];
    for (int b = threadIdx.x; b < nbuk; b += blockDim.x) h[b] = 0;
    __syncthreads();
    int stride = gridDim.x * blockDim.x;
    for (int e = blockIdx.x * blockDim.x + threadIdx.x; e < E; e += stride)
        atomicAdd(&h[ei[E + e] >> BSH], 1);
    __syncthreads();
    for (int b = threadIdx.x; b < nbuk; b += blockDim.x)
        if (h[b]) atomicAdd(&bcnt[b], h[b]);
}

// ---------------- exclusive scan of fine counts + superbucket bases ----------------
__global__ void k_scan(const int* __restrict__ bcnt, int nbuk, int E, int nsb,
                       int* __restrict__ bbase, int* __restrict__ cursor,
                       int* __restrict__ sbase, int* __restrict__ scursor) {
    __shared__ int s0[MAXBUK], s1[MAXBUK];
    int tid = threadIdx.x;
    for (int i = tid; i < MAXBUK; i += blockDim.x) s0[i] = (i < nbuk) ? bcnt[i] : 0;
    __syncthreads();
    int* src = s0; int* dst = s1;
    for (int off = 1; off < MAXBUK; off <<= 1) {
        for (int i = tid; i < MAXBUK; i += blockDim.x)
            dst[i] = src[i] + ((i >= off) ? src[i - off] : 0);
        __syncthreads();
        int* t = src; src = dst; dst = t;
    }
    // src[] holds the inclusive scan
    for (int i = tid; i < nbuk; i += blockDim.x) {
        int excl = src[i] - bcnt[i];
        bbase[i] = excl;
        cursor[i] = excl;
    }
    if (tid == 0) bbase[nbuk] = E;
    for (int i = tid; i <= nsb; i += blockDim.x) {
        int idx = i << 6;
        int v = (idx < nbuk) ? (src[idx] - bcnt[idx]) : E;
        sbase[i] = v;
        if (i < nsb) scursor[i] = v;
    }
}

// ---------------- pass 1: bin into 31 superbuckets ----------------
// tmp[pos] = (row << SSH) | (col & (SBW-1)); chunk = 4096 -> ~132-edge runs
__global__ void k_bin1(const int* __restrict__ ei, int E,
                       int* __restrict__ scursor, unsigned int* __restrict__ tmp) {
    __shared__ int colc[CMAX];
    __shared__ int h[MAXSB], base[MAXSB];
    int start = (int)blockIdx.x * CMAX;
    int end = min(start + CMAX, E);
    int cnt = end - start;
    if (threadIdx.x < MAXSB) h[threadIdx.x] = 0;
    __syncthreads();
    for (int i = threadIdx.x; i < cnt; i += blockDim.x) {
        int c = ei[E + start + i];
        colc[i] = c;
        atomicAdd(&h[c >> SSH], 1);
    }
    __syncthreads();
    if (threadIdx.x < MAXSB) {
        int c = h[threadIdx.x];
        base[threadIdx.x] = c ? atomicAdd(&scursor[threadIdx.x], c) : 0;
        h[threadIdx.x] = 0;                     // reuse as local cursor
    }
    __syncthreads();
    for (int i = threadIdx.x; i < cnt; i += blockDim.x) {
        int r = ei[start + i];
        int c = colc[i];
        int sb = c >> SSH;
        int loc = atomicAdd(&h[sb], 1);
        tmp[base[sb] + loc] = ((unsigned)r << SSH) | (unsigned)(c & (SBW - 1));
    }
}

// ---------------- pass 2: refine each superbucket into 64 fine buckets ----------------
// pairs[pos] = (row << BSH) | (col & (BW-1)), grouped by fine bucket. Order within a
// bucket is non-deterministic; all consumers accumulate in f64 (order-insensitive).
__global__ void k_bin2(const unsigned int* __restrict__ tmp, const int* __restrict__ sbase,
                       int* __restrict__ cursor, unsigned int* __restrict__ pairs) {
    __shared__ unsigned int cache[CMAX];
    __shared__ int h[64], base[64];
    int sb = blockIdx.x;
    int s = sbase[sb], e = sbase[sb + 1];
    int cnt = e - s;
    int chunk = (cnt + (int)gridDim.y - 1) / (int)gridDim.y;
    int start = s + (int)blockIdx.y * chunk;
    int end = min(start + chunk, e);
    int m = max(0, end - start);
    if (threadIdx.x < 64) h[threadIdx.x] = 0;
    __syncthreads();
    for (int i = threadIdx.x; i < m; i += blockDim.x) {
        unsigned v = tmp[start + i];
        cache[i] = v;
        atomicAdd(&h[(v & (SBW - 1u)) >> BSH], 1);
    }
    __syncthreads();
    if (threadIdx.x < 64) {
        int c = h[threadIdx.x];
        int fine = (sb << 6) + threadIdx.x;
        base[threadIdx.x] = c ? atomicAdd(&cursor[fine], c) : 0;
        h[threadIdx.x] = 0;                     // reuse as local cursor
    }
    __syncthreads();
    for (int i = threadIdx.x; i < m; i += blockDim.x) {
        unsigned v = cache[i];
        unsigned colLow = v & (SBW - 1u);
        int lb = (int)(colLow >> BSH);
        int loc = atomicAdd(&h[lb], 1);
        pairs[base[lb] + loc] = ((v >> SSH) << BSH) | (colLow & (BW - 1u));
    }
}

// ---------------- per-bucket degree count -> dinv + s4 (fused) ----------------
__global__ void k_dcnt(const unsigned int* __restrict__ pairs, const int* __restrict__ bbase,
                       const float* __restrict__ x, const float* __restrict__ y1, int n,
                       float* __restrict__ dinv, float4* __restrict__ s4) {
    __shared__ int cnt[BW];
    int b = blockIdx.x;
    if (threadIdx.x < BW) cnt[threadIdx.x] = 0;
    __syncthreads();
    int s = bbase[b], e = bbase[b + 1];
    for (int j = s + threadIdx.x; j < e; j += blockDim.x)
        atomicAdd(&cnt[pairs[j] & (BW - 1u)], 1);
    __syncthreads();
    if (threadIdx.x < BW) {
        int col = (b << BSH) + threadIdx.x;
        if (col < n) {
            float d = rsqrtf((float)cnt[threadIdx.x] + 1.0f);
            dinv[col] = d;
            s4[col] = make_float4(d * x[2 * col], d * x[2 * col + 1], d * y1[col], d);
        }
    }
}

// ---------------- fused layer 1: agg3 -> W1+ReLU -> W2*dinv -> hs2 ----------------
__global__ void k_L1(const unsigned int* __restrict__ pairs, const int* __restrict__ bbase,
                     const float4* __restrict__ s4, const float* __restrict__ W1,
                     const float* __restrict__ b1, const float* __restrict__ W2,
                     float* __restrict__ hs2, int n) {
    __shared__ double acc[BW * 3];
    int b = blockIdx.x;
    for (int i = threadIdx.x; i < BW * 3; i += blockDim.x) acc[i] = 0.0;
    __syncthreads();
    int s = bbase[b], e = bbase[b + 1];
    int j = s + threadIdx.x * 4;
    int stride = blockDim.x * 4;
    for (; j + 3 < e; j += stride) {
        unsigned pk0 = pairs[j], pk1 = pairs[j + 1], pk2 = pairs[j + 2], pk3 = pairs[j + 3];
        float4 v0 = s4[pk0 >> BSH];             // independent 16B gathers (L2-resident)
        float4 v1 = s4[pk1 >> BSH];
        float4 v2 = s4[pk2 >> BSH];
        float4 v3 = s4[pk3 >> BSH];
        int c0 = (int)(pk0 & (BW - 1u)) * 3, c1 = (int)(pk1 & (BW - 1u)) * 3;
        int c2 = (int)(pk2 & (BW - 1u)) * 3, c3 = (int)(pk3 & (BW - 1u)) * 3;
        atomicAdd(&acc[c0 + 0], (double)v0.x);
        atomicAdd(&acc[c0 + 1], (double)v0.y);
        atomicAdd(&acc[c0 + 2], (double)v0.z);
        atomicAdd(&acc[c1 + 0], (double)v1.x);
        atomicAdd(&acc[c1 + 1], (double)v1.y);
        atomicAdd(&acc[c1 + 2], (double)v1.z);
        atomicAdd(&acc[c2 + 0], (double)v2.x);
        atomicAdd(&acc[c2 + 1], (double)v2.y);
        atomicAdd(&acc[c2 + 2], (double)v2.z);
        atomicAdd(&acc[c3 + 0], (double)v3.x);
        atomicAdd(&acc[c3 + 1], (double)v3.y);
        atomicAdd(&acc[c3 + 2], (double)v3.z);
    }
    if (j < e) {
        int lim = min(j + 4, e);
        for (int t = j; t < lim; ++t) {
            unsigned pk = pairs[t];
            float4 v = s4[pk >> BSH];
            int c = (int)(pk & (BW - 1u)) * 3;
            atomicAdd(&acc[c + 0], (double)v.x);
            atomicAdd(&acc[c + 1], (double)v.y);
            atomicAdd(&acc[c + 2], (double)v.z);
        }
    }
    __syncthreads();
    int f = threadIdx.x & 31;
    int g = threadIdx.x >> 5;                   // 8 groups of 32
    for (int ci = g; ci < BW; ci += 8) {
        int col = (b << BSH) + ci;
        if (col >= n) continue;                 // group-uniform
        float4 sc = s4[col];
        float a0 = (float)acc[ci * 3 + 0] + sc.x;   // + self loop
        float a1 = (float)acc[ci * 3 + 1] + sc.y;
        float a2 = (float)acc[ci * 3 + 2] + sc.z;
        float d = sc.w;
        float t = a0 * W1[f] + a1 * W1[32 + f] + a2 * W1[64 + f];
        float h1 = fmaxf(d * t + b1[f], 0.0f);
        float o = 0.0f;
#pragma unroll
        for (int k = 0; k < 32; ++k)
            o += __shfl(h1, k, 32) * W2[k * 32 + f];
        hs2[(size_t)col * 32 + f] = d * o;
    }
}

// ---------------- fused layer 2 + layer-3 transform: agg32 -> ReLU -> W3 -> hs3 ----------------
__global__ void k_L2(const unsigned int* __restrict__ pairs, const int* __restrict__ bbase,
                     const float* __restrict__ hs2, const float* __restrict__ dinv,
                     const float* __restrict__ b2, const float* __restrict__ W3,
                     float* __restrict__ hs3, int n) {
    __shared__ double acc[BW * 32];             // 32 KB -> 4 blocks/CU
    int b = blockIdx.x;
    for (int i = threadIdx.x; i < BW * 32; i += blockDim.x) acc[i] = 0.0;
    __syncthreads();
    int s = bbase[b], e = bbase[b + 1];
    int f = threadIdx.x & 31;
    int g = threadIdx.x >> 5;                   // 16 groups of 32 (512 threads)
    int j = s + (g << 3);
    for (; j + 7 < e; j += 128) {               // 8-deep MLP per group
        unsigned pk0 = pairs[j],     pk1 = pairs[j + 1], pk2 = pairs[j + 2], pk3 = pairs[j + 3];
        unsigned pk4 = pairs[j + 4], pk5 = pairs[j + 5], pk6 = pairs[j + 6], pk7 = pairs[j + 7];
        float v0 = hs2[(size_t)(pk0 >> BSH) * 32 + f];   // 8 independent 128B gathers
        float v1 = hs2[(size_t)(pk1 >> BSH) * 32 + f];
        float v2 = hs2[(size_t)(pk2 >> BSH) * 32 + f];
        float v3 = hs2[(size_t)(pk3 >> BSH) * 32 + f];
        float v4 = hs2[(size_t)(pk4 >> BSH) * 32 + f];
        float v5 = hs2[(size_t)(pk5 >> BSH) * 32 + f];
        float v6 = hs2[(size_t)(pk6 >> BSH) * 32 + f];
        float v7 = hs2[(size_t)(pk7 >> BSH) * 32 + f];
        atomicAdd(&acc[(pk0 & (BW - 1u)) * 32 + f], (double)v0);
        atomicAdd(&acc[(pk1 & (BW - 1u)) * 32 + f], (double)v1);
        atomicAdd(&acc[(pk2 & (BW - 1u)) * 32 + f], (double)v2);
        atomicAdd(&acc[(pk3 & (BW - 1u)) * 32 + f], (double)v3);
        atomicAdd(&acc[(pk4 & (BW - 1u)) * 32 + f], (double)v4);
        atomicAdd(&acc[(pk5 & (BW - 1u)) * 32 + f], (double)v5);
        atomicAdd(&acc[(pk6 & (BW - 1u)) * 32 + f], (double)v6);
        atomicAdd(&acc[(pk7 & (BW - 1u)) * 32 + f], (double)v7);
    }
    if (j < e) {
        int lim = min(j + 8, e);
        for (int t = j; t < lim; ++t) {
            unsigned pk = pairs[t];
            float v = hs2[(size_t)(pk >> BSH) * 32 + f];
            atomicAdd(&acc[(pk & (BW - 1u)) * 32 + f], (double)v);
        }
    }
    __syncthreads();
    for (int ci = g; ci < BW; ci += 16) {
        int col = (b << BSH) + ci;
        if (col >= n) continue;
        float d = dinv[col];
        float h2 = fmaxf(d * ((float)acc[ci * 32 + f] + hs2[(size_t)col * 32 + f]) + b2[f], 0.0f);
        float w = h2 * W3[f];
        for (int off = 16; off > 0; off >>= 1) w += __shfl_down(w, off, 32);
        if (f == 0) hs3[col] = d * w;
    }
}

// ---------------- layer 3 aggregate: scalar, hs3 is 1MB L2-resident ----------------
__global__ void k_L3(const unsigned int* __restrict__ pairs, const int* __restrict__ bbase,
                     const float* __restrict__ hs3, const float* __restrict__ dinv,
                     const float* __restrict__ b3, float* __restrict__ out, int n) {
    __shared__ double acc[BW];
    int b = blockIdx.x;
    if (threadIdx.x < BW) acc[threadIdx.x] = 0.0;
    __syncthreads();
    int s = bbase[b], e = bbase[b + 1];
    int j = s + threadIdx.x * 4;
    int stride = blockDim.x * 4;
    for (; j + 3 < e; j += stride) {
        unsigned pk0 = pairs[j], pk1 = pairs[j + 1], pk2 = pairs[j + 2], pk3 = pairs[j + 3];
        float v0 = hs3[pk0 >> BSH];
        float v1 = hs3[pk1 >> BSH];
        float v2 = hs3[pk2 >> BSH];
        float v3 = hs3[pk3 >> BSH];
        atomicAdd(&acc[pk0 & (BW - 1u)], (double)v0);
        atomicAdd(&acc[pk1 & (BW - 1u)], (double)v1);
        atomicAdd(&acc[pk2 & (BW - 1u)], (double)v2);
        atomicAdd(&acc[pk3 & (BW - 1u)], (double)v3);
    }
    if (j < e) {
        int lim = min(j + 4, e);
        for (int t = j; t < lim; ++t) {
            unsigned pk = pairs[t];
            atomicAdd(&acc[pk & (BW - 1u)], (double)hs3[pk >> BSH]);
        }
    }
    __syncthreads();
    int col = (b << BSH) + threadIdx.x;
    if (threadIdx.x < BW && col < n)
        out[col] = dinv[col] * ((float)acc[threadIdx.x] + hs3[col]) + b3[0];
}

// ---------------- launch ----------------

extern "C" void kernel_launch(void* const* d_in, const int* in_sizes, int n_in,
                              void* d_out, int out_size, void* d_ws, size_t ws_size,
                              hipStream_t stream) {
    const float* x  = (const float*)d_in[0];
    const float* y1 = (const float*)d_in[1];
    const int*   ei = (const int*)d_in[2];
    const float* W1 = (const float*)d_in[3];
    const float* b1 = (const float*)d_in[4];
    const float* W2 = (const float*)d_in[5];
    const float* b2 = (const float*)d_in[6];
    const float* W3 = (const float*)d_in[7];
    const float* b3 = (const float*)d_in[8];
    float* out = (float*)d_out;

    const int n = in_sizes[1];          // 250000
    const int E = in_sizes[2] / 2;      // 8000000
    const int nbuk = (n + BW - 1) >> BSH;   // 1954
    const int nsb = (nbuk + 63) >> 6;       // 31 superbuckets

    char* ws = (char*)d_ws;
    size_t off = 0;
    auto alloc = [&](size_t bytes) { char* p = ws + off; off += (bytes + 255) & ~(size_t)255; return p; };
    unsigned int* pairs = (unsigned int*)alloc((size_t)E * sizeof(unsigned int)); // 32MB
    float*  hs2   = (float*)alloc((size_t)n * 32 * sizeof(float));               // 32MB
    float4* s4    = (float4*)alloc((size_t)n * sizeof(float4));                  // 4MB
    float*  dinv  = (float*)alloc((size_t)n * sizeof(float));
    float*  hs3   = (float*)alloc((size_t)n * sizeof(float));
    int*    bcnt  = (int*)alloc((size_t)nbuk * sizeof(int));
    int*    bbase = (int*)alloc((size_t)(nbuk + 1) * sizeof(int));
    int*    cursor= (int*)alloc((size_t)nbuk * sizeof(int));
    int*    sbase = (int*)alloc((size_t)(nsb + 1) * sizeof(int));
    int*    scursor = (int*)alloc((size_t)nsb * sizeof(int));
    (void)ws_size;
    // tmp (pass-1 output) aliases hs2: tmp is dead before k_L1 writes hs2 (both 32MB).
    unsigned int* tmp = (unsigned int*)hs2;

    // fine histogram + scans
    hipMemsetAsync(bcnt, 0, (size_t)nbuk * sizeof(int), stream);
    k_hist<<<1024, 256, 0, stream>>>(ei, E, nbuk, bcnt);
    k_scan<<<1, 1024, 0, stream>>>(bcnt, nbuk, E, nsb, bbase, cursor, sbase, scursor);

    // two-pass radix partition (high-occupancy grids)
    const int nbin1 = (E + CMAX - 1) / CMAX;    // 1954 blocks
    k_bin1<<<nbin1, 256, 0, stream>>>(ei, E, scursor, tmp);
    k_bin2<<<dim3(nsb, 72), 256, 0, stream>>>(tmp, sbase, cursor, pairs);

    // degree -> dinv + s4 (fused)
    k_dcnt<<<nbuk, 256, 0, stream>>>(pairs, bbase, x, y1, n, dinv, s4);

    // fused layers
    k_L1<<<nbuk, 256, 0, stream>>>(pairs, bbase, s4, W1, b1, W2, hs2, n);
    k_L2<<<nbuk, 512, 0, stream>>>(pairs, bbase, hs2, dinv, b2, W3, hs3, n);
    k_L3<<<nbuk, 256, 0, stream>>>(pairs, bbase, hs3, dinv, b3, out, n);
}